// Round 11
// baseline (4740.260 us; speedup 1.0000x reference)
//
#include <hip/hip_runtime.h>
#include <stdint.h>

typedef _Float16 f16;
typedef _Float16 f16x8 __attribute__((ext_vector_type(8)));
typedef float f32x4 __attribute__((ext_vector_type(4)));

#define BATCH 256
#define SEQ   128
#define EMB   300
#define HID   1024
#define OUTD  20
#define CAT   1324          // HID + EMB
#define KE    1344          // padded K: 1024 (c) + 320 (x incl bias-1, zero pad)
#define XP    320           // xe row: 300 emb + [300]=1.0 + zeros
#define LSTR  1352          // LDS weight row stride
#define ASTR  1032          // LDS A-slab row stride (516 dwords = 4 mod 32 -> uniform banks)
#define BPG   32            // blocks per group
#define MPG   32            // batch rows per group

__device__ __forceinline__ float sigm(float z)  { return 1.f / (1.f + __expf(-z)); }
__device__ __forceinline__ float tanhf_(float z){ float e = __expf(2.f * z); return 1.f - 2.f / (e + 1.f); }

#define MFMA(a,b,c) __builtin_amdgcn_mfma_f32_16x16x32_f16((a),(b),(c),0,0,0)

// ---------------------------------------------------------------------------
// Weight packing: Wru_e[2048][1344] (rows 0..1023 = W_r|b_r, 1024..2047 = W_u|b_u)
//                 Wc_e[1024][1344], Wp_e[32][1024] (rows >=20 zero)
// ---------------------------------------------------------------------------
__global__ void pack_kernel(const float* __restrict__ Wr, const float* __restrict__ br,
                            const float* __restrict__ Wu, const float* __restrict__ bu,
                            const float* __restrict__ Wc, const float* __restrict__ bc,
                            const float* __restrict__ Wp,
                            f16* __restrict__ Wru_e, f16* __restrict__ Wc_e, f16* __restrict__ Wp_e)
{
    const int NRU = 2048 * KE, NC = 1024 * KE, NP = 32 * HID;
    for (int idx = blockIdx.x * blockDim.x + threadIdx.x; idx < NRU + NC + NP;
         idx += gridDim.x * blockDim.x) {
        if (idx < NRU) {
            int n = idx / KE, k = idx - n * KE;
            const float* Ws = (n < HID) ? Wr : Wu;
            const float* bs = (n < HID) ? br : bu;
            int row = n & (HID - 1);
            float v = (k < CAT) ? Ws[(size_t)row * CAT + k] : ((k == CAT) ? bs[row] : 0.f);
            Wru_e[idx] = (f16)v;
        } else if (idx < NRU + NC) {
            int j = idx - NRU;
            int n = j / KE, k = j - n * KE;
            float v = (k < CAT) ? Wc[(size_t)n * CAT + k] : ((k == CAT) ? bc[n] : 0.f);
            Wc_e[j] = (f16)v;
        } else {
            int j = idx - NRU - NC;
            int n = j / HID, k = j & (HID - 1);
            Wp_e[j] = (n < OUTD) ? (f16)Wp[(size_t)n * HID + k] : (f16)(0.f);
        }
    }
}

// ---------------------------------------------------------------------------
// Embedding gather: xe[t][b][0..319] f16 : emb row, 1.0 at [300], zeros after
// ---------------------------------------------------------------------------
__global__ void gather_kernel(const int* __restrict__ x, const float* __restrict__ emb,
                              f16* __restrict__ xe)
{
    const int TOT = SEQ * BATCH * XP;
    for (int idx = blockIdx.x * blockDim.x + threadIdx.x; idx < TOT;
         idx += gridDim.x * blockDim.x) {
        int e  = idx % XP;
        int rb = idx / XP;
        int b  = rb & 255, t = rb >> 8;
        float v;
        if (e < EMB) { int id = x[b * SEQ + t]; v = emb[(size_t)id * EMB + e]; }
        else          v = (e == EMB) ? 1.f : 0.f;
        xe[idx] = (f16)v;
    }
}

__global__ void zero_kernel(uint32_t* __restrict__ c0, int n0, uint32_t* __restrict__ bar, int nb)
{
    for (int i = blockIdx.x * blockDim.x + threadIdx.x; i < n0; i += gridDim.x * blockDim.x)
        c0[i] = 0u;
    if (blockIdx.x == 0)
        for (int i = threadIdx.x; i < nb; i += blockDim.x) bar[i] = 0u;
}

// ---------------------------------------------------------------------------
// PROVEN relay barrier (r7/r8 agent-fenced path, unconditional):
// arrive: syncthreads (drains vmcnt) -> release fence -> relaxed flag store.
// check (one wave): poll 32 flags -> acquire+release fences -> go store.
// wait: poll go -> acquire fence -> syncthreads.
// ---------------------------------------------------------------------------
__device__ __forceinline__ void bar_arrive(int* slot, int ep)
{
    __syncthreads();
    if (threadIdx.x == 0) {
        __builtin_amdgcn_fence(__ATOMIC_RELEASE, "agent");
        __hip_atomic_store(slot, ep, __ATOMIC_RELAXED, __HIP_MEMORY_SCOPE_AGENT);
    }
}
__device__ __forceinline__ void bar_check(int* arrg, int* go, int ep, int lane)
{
    int spins = 0;
    while (!__all(__hip_atomic_load(&arrg[lane & 31], __ATOMIC_RELAXED,
                                    __HIP_MEMORY_SCOPE_AGENT) >= ep)) {
        __builtin_amdgcn_s_sleep(1);
        if (++spins > (1 << 24)) break;   // anti-hang valve
    }
    __builtin_amdgcn_fence(__ATOMIC_ACQUIRE, "agent");
    __builtin_amdgcn_fence(__ATOMIC_RELEASE, "agent");
    if (lane == 0)
        __hip_atomic_store(go, ep, __ATOMIC_RELAXED, __HIP_MEMORY_SCOPE_AGENT);
}
__device__ __forceinline__ void bar_wait(int* go, int ep)
{
    if (threadIdx.x == 0) {
        int spins = 0;
        while (__hip_atomic_load(go, __ATOMIC_RELAXED, __HIP_MEMORY_SCOPE_AGENT) < ep) {
            __builtin_amdgcn_s_sleep(1);
            if (++spins > (1 << 24)) break;
        }
        __builtin_amdgcn_fence(__ATOMIC_ACQUIRE, "agent");
    }
    __syncthreads();
}

// ---------------------------------------------------------------------------
// A-slab: 32 rows x 1024 f16 in LDS at padded stride ASTR=1032 (uniform
// banks for column b128 reads). Stage = 2 batches of 8 indep 16B loads/thr
// (16-deep MLP, block-cooperative — no per-wave latency chains, 4x dedup).
// ---------------------------------------------------------------------------
__device__ __forceinline__ void stage_slab(const f16* __restrict__ src, f16* dst, int tid)
{
    #pragma unroll
    for (int half = 0; half < 2; ++half) {
        f16x8 buf[8];
        #pragma unroll
        for (int i = 0; i < 8; ++i) {
            int c = tid + 256 * (half * 8 + i);      // chunk id in [0,4096)
            int r = c >> 7, j = c & 127;
            buf[i] = *(const f16x8*)(src + (size_t)r * 1024 + j * 8);
        }
        #pragma unroll
        for (int i = 0; i < 8; ++i) {
            int c = tid + 256 * (half * 8 + i);
            int r = c >> 7, j = c & 127;
            *(f16x8*)(dst + (size_t)r * ASTR + j * 8) = buf[i];
        }
    }
}

// ---- K-loops: A from LDS slab (a0 pre-offset by row*ASTR + ko), B from LDS
// weights or global (bp pre-offset by row; advances 32 f16 per kc) ----------
__device__ __forceinline__ void kloopA2(const f16* a0, const f16* bp,
                                        f32x4& acc0, f32x4& acc1)
{
    const f16* a1 = a0 + (size_t)16 * ASTR;
    #pragma unroll
    for (int h = 0; h < 4; ++h) {
        f16x8 B[8];
        #pragma unroll
        for (int i = 0; i < 8; ++i) B[i] = *(const f16x8*)(bp + (h * 8 + i) * 32);
        #pragma unroll
        for (int i = 0; i < 8; ++i) {
            const int kc = h * 8 + i;
            acc0 = MFMA(*(const f16x8*)(a0 + kc * 32), B[i], acc0);
            acc1 = MFMA(*(const f16x8*)(a1 + kc * 32), B[i], acc1);
        }
    }
}
__device__ __forceinline__ void kloopA1(const f16* a, const f16* bp, f32x4& acc)
{
    #pragma unroll
    for (int h = 0; h < 4; ++h) {
        f16x8 B[8];
        #pragma unroll
        for (int i = 0; i < 8; ++i) B[i] = *(const f16x8*)(bp + (h * 8 + i) * 32);
        #pragma unroll
        for (int i = 0; i < 8; ++i)
            acc = MFMA(*(const f16x8*)(a + (h * 8 + i) * 32), B[i], acc);
    }
}
__device__ __forceinline__ void xpart2(const f16* xa0, const f16* xa1, const f16* bp,
                                       f32x4& acc0, f32x4& acc1)
{
    #pragma unroll
    for (int kc = 0; kc < 10; ++kc) {
        f16x8 B = *(const f16x8*)(bp + 1024 + kc * 32);
        acc0 = MFMA(*(const f16x8*)(xa0 + kc * 32), B, acc0);
        acc1 = MFMA(*(const f16x8*)(xa1 + kc * 32), B, acc1);
    }
}
__device__ __forceinline__ void xpart1(const f16* xa, const f16* bp, f32x4& acc)
{
    #pragma unroll
    for (int kc = 0; kc < 10; ++kc)
        acc = MFMA(*(const f16x8*)(xa + kc * 32),
                   *(const f16x8*)(bp + 1024 + kc * 32), acc);
}

// ---------------------------------------------------------------------------
// Persistent recurrence (r8 structure + LDS A-slab, LDS under 128 KiB).
// 256 blocks x 256 thr, cooperative. 8 groups x 32 blocks: g = blockIdx&7,
// gblk = blockIdx>>3. Group owns batch rows [g*32,+32).
// LDS: 16 Wru rows (wave 0's gates B) + 32x1024 A-slab = 109,312 B.
// Per phase the block stages the 64 KB A-slab (Ct or RC) cooperatively;
// K-loops read A from LDS. Gates: block n-cols [gblk*64,+64), wave wv =
// n-tile (wv==0 B from LDS, else L2-global), both m-tiles. Update: block
// n-cols [gblk*32,+32), wave: m-tile wv&1, n-tile wv>>1, B from global.
// ---------------------------------------------------------------------------
__global__ __launch_bounds__(256) void rnn_kernel(
    const f16* __restrict__ xe,  const f16* __restrict__ Wru,
    const f16* __restrict__ Wc,  const f16* __restrict__ Wp,
    const float* __restrict__ bpred, f16* __restrict__ Call,
    float* __restrict__ U, f16* __restrict__ RC,
    int* __restrict__ bar, float* __restrict__ out)
{
    extern __shared__ char smem[];
    f16* ldsRU = (f16*)smem;                    // 16 x LSTR : Wru rows [N0,N0+16)
    f16* slabA = ldsRU + 16 * LSTR;             // 32 x ASTR A-slab

    const int tid  = threadIdx.x;
    const int lane = tid & 63;
    const int wv   = tid >> 6;
    const int q    = lane >> 4;
    const int cx   = lane & 15;
    const int ko   = q * 8;
    const int g    = blockIdx.x & 7;
    const int gblk = blockIdx.x >> 3;
    const int mG   = g * MPG;
    const int N0   = gblk * 64;                 // gates n-base
    const int M0   = gblk * 32;                 // update n-base
    const int jm   = wv & 1;

    int* arrg = bar + 64 + g * BPG;
    int* slot = arrg + gblk;
    int* go   = bar + 384 + g * 16;
    const int is_chk = (gblk == 0 && wv == 0);

    // ---- stage LDS weights (once) + initial A-slab (Ct = slot 0) -----------
    {
        const f16* gRU = Wru + (size_t)N0 * KE;
        for (int i = tid; i < 16 * (KE / 8); i += 256) {
            int r = i / (KE / 8), c = i % (KE / 8);
            *(f16x8*)(ldsRU + r * LSTR + c * 8) = *(const f16x8*)(gRU + (size_t)r * KE + c * 8);
        }
        stage_slab(Call + (size_t)mG * HID, slabA, tid);
        __syncthreads();
    }

    // wave-uniform pointers
    const f16* aG  = slabA + (size_t)cx * ASTR + ko;                  // gates A (m-tile 0; +16*ASTR = tile 1)
    const f16* aU  = slabA + (size_t)(jm * 16 + cx) * ASTR + ko;      // update A
    const f16* bG  = (wv == 0) ? (const f16*)(ldsRU + (size_t)cx * LSTR + ko)
                               : (const f16*)(Wru + (size_t)(N0 + wv * 16 + cx) * KE + ko);
    const f16* bUg = Wc + (size_t)(M0 + (wv >> 1) * 16 + cx) * KE + ko; // update B (L2)
    const int  nG  = N0 + wv * 16 + cx;
    const int  nU  = M0 + (wv >> 1) * 16 + cx;

    // prologue: gates x-part for t=0
    f32x4 gx0 = {0.f,0.f,0.f,0.f}, gx1 = {0.f,0.f,0.f,0.f};
    xpart2(xe + (size_t)(mG + cx) * XP + ko,
           xe + (size_t)(mG + 16 + cx) * XP + ko, bG, gx0, gx1);

    int ep = 0;
    for (int t = 0; t < SEQ; ++t) {
        const f16* Ct  = Call + (size_t)t * BATCH * HID;
        f16*       Ct1 = Call + (size_t)(t + 1) * BATCH * HID;
        const f16* xet = xe   + (size_t)t * BATCH * XP;

        // ================= gates phase (A-slab holds Ct) ====================
        {
            f32x4 acc0 = gx0, acc1 = gx1;
            kloopA2(aG, bG, acc0, acc1);

            if (N0 < HID) {          // r-gate -> RC ; c_prev from the slab
                #pragma unroll
                for (int jt = 0; jt < 2; ++jt) {
                    const f32x4& ac = jt ? acc1 : acc0;
                    #pragma unroll
                    for (int r = 0; r < 4; ++r) {
                        int ml = jt * 16 + q * 4 + r;
                        float c = (float)slabA[(size_t)ml * ASTR + nG];
                        *(volatile f16*)&RC[(size_t)(mG + ml) * HID + nG]
                            = (f16)(sigm(ac[r]) * c);
                    }
                }
            } else {                 // u-gate -> U
                #pragma unroll
                for (int jt = 0; jt < 2; ++jt) {
                    const f32x4& ac = jt ? acc1 : acc0;
                    #pragma unroll
                    for (int r = 0; r < 4; ++r) {
                        int ml = jt * 16 + q * 4 + r;
                        *(volatile float*)&U[(size_t)(mG + ml) * HID + (nG - HID)]
                            = sigm(ac[r]);
                    }
                }
            }
        }
        ++ep;
        bar_arrive(slot, ep);
        f32x4 ux = {0.f,0.f,0.f,0.f};
        if (is_chk) bar_check(arrg, go, ep, lane);
        xpart1(xet + (size_t)(mG + jm * 16 + cx) * XP + ko, bUg, ux);
        bar_wait(go, ep);

        // ================= update phase (re-stage slab with RC) =============
        stage_slab(RC + (size_t)mG * HID, slabA, tid);
        __syncthreads();
        {
            f32x4 acc = ux;
            kloopA1(aU, bUg, acc);
            #pragma unroll
            for (int r = 0; r < 4; ++r) {
                int m = mG + jm * 16 + q * 4 + r;
                float u = *(volatile const float*)&U[(size_t)m * HID + nU];
                float c = (float)Ct[(size_t)m * HID + nU];
                float cct = tanhf_(acc[r]);
                *(volatile f16*)&Ct1[(size_t)m * HID + nU] = (f16)(u * cct + (1.f - u) * c);
            }
        }
        ++ep;
        bar_arrive(slot, ep);
        gx0 = (f32x4){0.f,0.f,0.f,0.f};
        gx1 = (f32x4){0.f,0.f,0.f,0.f};
        if (is_chk) bar_check(arrg, go, ep, lane);
        if (t + 1 < SEQ) {
            const f16* xn = xe + (size_t)(t + 1) * BATCH * XP;
            xpart2(xn + (size_t)(mG + cx) * XP + ko,
                   xn + (size_t)(mG + 16 + cx) * XP + ko, bG, gx0, gx1);
        }
        bar_wait(go, ep);

        // re-stage slab with the new state for the next gates phase
        if (t + 1 < SEQ) {
            stage_slab(Ct1 + (size_t)mG * HID, slabA, tid);
            __syncthreads();
        }
    }

    // ---- prediction (group-local, r8-verbatim): out = C[t+1].Wp^T + bp -----
    #pragma unroll
    for (int i = 0; i < 2; ++i) {
        const int mt = gblk * 8 + wv * 2 + i;    // [0,256) group bt-tile
        const int tt = mt >> 1;
        const int bb = mG + (mt & 1) * 16;
        const f16* ap  = Call + (size_t)(tt + 1) * BATCH * HID + (size_t)(bb + cx) * HID + ko;
        const f16* wp0 = Wp + (size_t)cx * HID + ko;
        const f16* wp1 = Wp + (size_t)(16 + cx) * HID + ko;
        f32x4 acc0 = {0.f,0.f,0.f,0.f}, acc1 = {0.f,0.f,0.f,0.f};
        f16x8 A[8], B0[8], B1[8];
        #pragma unroll
        for (int h = 0; h < 4; ++h) {
            #pragma unroll
            for (int j2 = 0; j2 < 8; ++j2) {
                const int kc = h * 8 + j2;
                A[j2]  = *(const f16x8*)(ap  + kc * 32);
                B0[j2] = *(const f16x8*)(wp0 + kc * 32);
                B1[j2] = *(const f16x8*)(wp1 + kc * 32);
            }
            #pragma unroll
            for (int j2 = 0; j2 < 8; ++j2) {
                acc0 = MFMA(A[j2], B0[j2], acc0);
                acc1 = MFMA(A[j2], B1[j2], acc1);
            }
        }
        #pragma unroll
        for (int nt = 0; nt < 2; ++nt) {
            const int o = nt * 16 + cx;
            if (o < OUTD) {
                const f32x4& ac = nt ? acc1 : acc0;
                #pragma unroll
                for (int r = 0; r < 4; ++r) {
                    const int brow = bb + q * 4 + r;
                    out[((size_t)brow * SEQ + tt) * OUTD + o] = ac[r] + bpred[o];
                }
            }
        }
    }
}

// ---------------------------------------------------------------------------
extern "C" void kernel_launch(void* const* d_in, const int* in_sizes, int n_in,
                              void* d_out, int out_size, void* d_ws, size_t ws_size,
                              hipStream_t stream)
{
    const int*   x   = (const int*)  d_in[0];
    const float* emb = (const float*)d_in[1];
    const float* Wr  = (const float*)d_in[2];
    const float* br  = (const float*)d_in[3];
    const float* Wu  = (const float*)d_in[4];
    const float* bu  = (const float*)d_in[5];
    const float* Wc  = (const float*)d_in[6];
    const float* bc  = (const float*)d_in[7];
    const float* Wp  = (const float*)d_in[8];
    const float* bp  = (const float*)d_in[9];

    // bar region FIRST: [64..320) arrival flags | [384..512) go flags (padded)
    char* p = (char*)d_ws;
    int* bar   = (int*)p;  p += 1024 * sizeof(int);
    f16* Wru_e = (f16*)p;  p += (size_t)2048 * KE * 2;
    f16* Wc_e  = (f16*)p;  p += (size_t)1024 * KE * 2;
    f16* Wp_e  = (f16*)p;  p += (size_t)32 * HID * 2;
    f16* xe    = (f16*)p;  p += (size_t)SEQ * BATCH * XP * 2;
    f16* Call  = (f16*)p;  p += (size_t)(SEQ + 1) * BATCH * HID * 2;  // slot 0 = zeros
    float* U   = (float*)p; p += (size_t)BATCH * HID * 4;
    f16* RC    = (f16*)p;  p += (size_t)BATCH * HID * 2;

    const int LDS_BYTES = 16 * LSTR * 2 + 32 * ASTR * 2;  // 43,264 + 66,048 = 109,312 (< 128 KiB)

    pack_kernel<<<2048, 256, 0, stream>>>(Wr, br, Wu, bu, Wc, bc, Wp, Wru_e, Wc_e, Wp_e);
    gather_kernel<<<4096, 256, 0, stream>>>(x, emb, xe);
    zero_kernel<<<256, 256, 0, stream>>>((uint32_t*)Call, BATCH * HID / 2, (uint32_t*)bar, 1024);

    hipFuncSetAttribute((const void*)rnn_kernel,
                        hipFuncAttributeMaxDynamicSharedMemorySize, LDS_BYTES);

    void* args[] = { &xe, &Wru_e, &Wc_e, &Wp_e, (void*)&bp, &Call, &U, &RC, &bar, &d_out };
    hipLaunchCooperativeKernel((const void*)rnn_kernel, dim3(256), dim3(256),
                               args, LDS_BYTES, stream);
}